// Round 3
// baseline (176.854 us; speedup 1.0000x reference)
//
#include <hip/hip_runtime.h>
#include <cstddef>

#define IMG 256
#define HW 65536
#define NB 4
#define NC_IN 48
#define NHEADS 8
#define TILE 14
#define HALO 16
#define NT 19          // ceil(256/14)
#define NTILES (NT*NT) // 361

typedef short bf16x8 __attribute__((ext_vector_type(8)));
typedef float f32x4 __attribute__((ext_vector_type(4)));
typedef float f32x16 __attribute__((ext_vector_type(16)));

__device__ __forceinline__ unsigned short f2bf(float f) {
    unsigned int x = __float_as_uint(f);
    unsigned int r = (x + 0x7fffu + ((x >> 16) & 1u)) >> 16;
    return (unsigned short)r;
}

// ---------------------------------------------------------------------------
// K1: ONE conv kernel for both paths.
//  - 16x16 halo tile (14x14 interior), 256 threads, 4 waves.
//  - 4 qk m-tiles (2 heads each: q6+k6+pad4 per head -> 32 MFMA rows) and
//    3 v m-tiles (16 real rows of 32). conv1x1 via mfma_f32_32x32x16_bf16.
//  - y LDS [256][28] f32: 112B rows (16B aligned); bank-start stride 28 -> even
//    8-group pattern (optimal); C written as float4 row-quads (conflict-even).
//  - dwconv3x3 on VALU from float4 y reads.
//  - qk: Gram/norm stats via 16x16x32 MFMA on per-wave bf16 staging, LDS+global atomics.
//  - v: dwconv result written f32 to v_buf.
// stats per b (384 f32): [0..47]=qq(h*6+c), [48..95]=kk, [96..]=h*36+cc*6+d
// ---------------------------------------------------------------------------
__global__ __launch_bounds__(256) void conv_all_kernel(
    const float* __restrict__ fea0, const float* __restrict__ fea1,
    const float* __restrict__ qk_w, const float* __restrict__ qk_dw,
    const float* __restrict__ v_w, const float* __restrict__ v_dw,
    float* __restrict__ v_buf, float* __restrict__ stats) {
    __shared__ float y[256][28];
    __shared__ __align__(16) unsigned short sg[4][28][72];
    __shared__ float sacc[384];

    const int tid = threadIdx.x;
    const int b = blockIdx.y;
    const int tx = blockIdx.x % NT, ty = blockIdx.x / NT;
    const int wave = tid >> 6, lane = tid & 63;
    const int l31 = lane & 31, lhi = lane >> 5;
    const int w64 = wave * 64;

    for (int i = tid; i < 384; i += 256) sacc[i] = 0.f;

    const float* fb0 = fea0 + (size_t)b * NC_IN * HW;
    const float* fb1 = fea1 + (size_t)b * NC_IN * HW;

    // ---- B fragments for both inputs (held in registers all kernel) ----
    bf16x8 Bf0[2][3], Bf1[2][3];
#pragma unroll
    for (int n = 0; n < 2; ++n) {
        const int px = w64 + n * 32 + l31;
        const int hx = px & 15, hy = px >> 4;
        const int gx = tx * TILE + hx - 1, gy = ty * TILE + hy - 1;
        const bool inb = ((unsigned)gx < (unsigned)IMG) && ((unsigned)gy < (unsigned)IMG);
        const int pix = inb ? (gy * IMG + gx) : 0;
#pragma unroll
        for (int ks = 0; ks < 3; ++ks) {
            const int ch0 = ks * 16 + lhi * 8;
            bf16x8 t0, t1;
#pragma unroll
            for (int j = 0; j < 8; ++j) {
                const float x0 = inb ? fb0[(size_t)(ch0 + j) * HW + pix] : 0.f;
                const float x1 = inb ? fb1[(size_t)(ch0 + j) * HW + pix] : 0.f;
                t0[j] = (short)f2bf(x0);
                t1[j] = (short)f2bf(x1);
            }
            Bf0[n][ks] = t0;
            Bf1[n][ks] = t1;
        }
    }

    // interior pixel for dwconv
    const int ilx = tid % TILE, ily = tid / TILE;
    const int gxi = tx * TILE + ilx, gyi = ty * TILE + ily;
    const bool valid = (tid < TILE * TILE) && (gxi < IMG) && (gyi < IMG);
    const int opix = gyi * IMG + gxi;

    // ======================= qk m-tiles (4 x 2 heads) =======================
    for (int m = 0; m < 4; ++m) {
        const int h0 = 2 * m;

        // A fragments: permuted+padded weight rows
        const int sub = l31 & 15;
        const int hh_ = h0 + (l31 >> 4);
        const bool wok = sub < 12;
        const int wr = (sub < 6) ? (hh_ * 6 + sub) : (48 + hh_ * 6 + (sub - 6));
        bf16x8 Af[3];
#pragma unroll
        for (int ks = 0; ks < 3; ++ks) {
            const int k0 = ks * 16 + lhi * 8;
            bf16x8 t;
            if (wok) {
                const float4 wa = *(const float4*)&qk_w[wr * 48 + k0];
                const float4 wb = *(const float4*)&qk_w[wr * 48 + k0 + 4];
                t[0] = (short)f2bf(wa.x); t[1] = (short)f2bf(wa.y);
                t[2] = (short)f2bf(wa.z); t[3] = (short)f2bf(wa.w);
                t[4] = (short)f2bf(wb.x); t[5] = (short)f2bf(wb.y);
                t[6] = (short)f2bf(wb.z); t[7] = (short)f2bf(wb.w);
            } else {
#pragma unroll
                for (int j = 0; j < 8; ++j) t[j] = 0;
            }
            Af[ks] = t;
        }

        f32x16 C0, C1;
#pragma unroll
        for (int r = 0; r < 16; ++r) { C0[r] = 0.f; C1[r] = 0.f; }
#pragma unroll
        for (int ks = 0; ks < 3; ++ks) {
            C0 = __builtin_amdgcn_mfma_f32_32x32x16_bf16(Af[ks], Bf0[0][ks], C0, 0, 0, 0);
            C1 = __builtin_amdgcn_mfma_f32_32x32x16_bf16(Af[ks], Bf0[1][ks], C1, 0, 0, 0);
        }

        __syncthreads();  // previous tile's y reads complete
        // write as float4 row-quads: rows r=4q+j map to ch base 8q+4lhi (+j)
#pragma unroll
        for (int q = 0; q < 4; ++q) {
            const int base = 8 * q + 4 * lhi;
            const int rsub = base & 15;
            if (rsub < 12) {
                const int ych = (base >> 4) * 12 + rsub;
                float4 a, c;
                a.x = C0[4 * q]; a.y = C0[4 * q + 1]; a.z = C0[4 * q + 2]; a.w = C0[4 * q + 3];
                c.x = C1[4 * q]; c.y = C1[4 * q + 1]; c.z = C1[4 * q + 2]; c.w = C1[4 * q + 3];
                *(float4*)&y[w64 + l31][ych] = a;
                *(float4*)&y[w64 + 32 + l31][ych] = c;
            }
        }
        __syncthreads();

        // depthwise 3x3 on 24 channels (2 heads)
        float qk2[24];
#pragma unroll
        for (int c = 0; c < 24; ++c) qk2[c] = 0.f;
        if (valid) {
#pragma unroll
            for (int dy = 0; dy < 3; ++dy)
#pragma unroll
                for (int dx = 0; dx < 3; ++dx) {
                    const int tap = dy * 3 + dx;
                    const float* yp = &y[(ily + dy) * HALO + (ilx + dx)][0];
                    float yv[24];
                    *(float4*)&yv[0]  = *(const float4*)(yp);
                    *(float4*)&yv[4]  = *(const float4*)(yp + 4);
                    *(float4*)&yv[8]  = *(const float4*)(yp + 8);
                    *(float4*)&yv[12] = *(const float4*)(yp + 12);
                    *(float4*)&yv[16] = *(const float4*)(yp + 16);
                    *(float4*)&yv[20] = *(const float4*)(yp + 20);
#pragma unroll
                    for (int c = 0; c < 24; ++c) {
                        const int hh = h0 + (c >= 12);
                        const int s = c - (c >= 12 ? 12 : 0);
                        const int dr = (s < 6) ? (hh * 6 + s) : (48 + hh * 6 + (s - 6));
                        qk2[c] = fmaf(qk_dw[dr * 9 + tap], yv[c], qk2[c]);
                    }
                }
        }

        // Gram stats via MFMA: per-wave staging [24ch x 64px] bf16
#pragma unroll
        for (int c = 0; c < 24; ++c) sg[wave][c][lane] = f2bf(qk2[c]);
        asm volatile("s_waitcnt lgkmcnt(0)" ::: "memory");
        __builtin_amdgcn_sched_barrier(0);
        const int fr = lane & 15, fg = lane >> 4;
#pragma unroll
        for (int hh = 0; hh < 2; ++hh) {
            const bf16x8 a0 = *(const bf16x8*)&sg[wave][hh * 12 + fr][fg * 8];
            const bf16x8 a1 = *(const bf16x8*)&sg[wave][hh * 12 + fr][32 + fg * 8];
            f32x4 c4 = {0.f, 0.f, 0.f, 0.f};
            c4 = __builtin_amdgcn_mfma_f32_16x16x32_bf16(a0, a0, c4, 0, 0, 0);
            c4 = __builtin_amdgcn_mfma_f32_16x16x32_bf16(a1, a1, c4, 0, 0, 0);
            const int h = h0 + hh;
#pragma unroll
            for (int r = 0; r < 4; ++r) {
                const int crow = fg * 4 + r;
                const float vv = c4[r];
                if (crow < 6) {
                    if (fr == crow) atomicAdd(&sacc[h * 6 + crow], vv);
                    else if (fr >= 6 && fr < 12)
                        atomicAdd(&sacc[96 + h * 36 + crow * 6 + (fr - 6)], vv);
                } else if (crow < 12 && fr == crow) {
                    atomicAdd(&sacc[48 + h * 6 + (crow - 6)], vv);
                }
            }
        }
    }

    // ======================= v m-tiles (3 x 16 ch) =======================
    for (int vt = 0; vt < 3; ++vt) {
        const bool wok = l31 < 16;
        const int wr = vt * 16 + l31;
        bf16x8 Af[3];
#pragma unroll
        for (int ks = 0; ks < 3; ++ks) {
            const int k0 = ks * 16 + lhi * 8;
            bf16x8 t;
            if (wok) {
                const float4 wa = *(const float4*)&v_w[wr * 48 + k0];
                const float4 wb = *(const float4*)&v_w[wr * 48 + k0 + 4];
                t[0] = (short)f2bf(wa.x); t[1] = (short)f2bf(wa.y);
                t[2] = (short)f2bf(wa.z); t[3] = (short)f2bf(wa.w);
                t[4] = (short)f2bf(wb.x); t[5] = (short)f2bf(wb.y);
                t[6] = (short)f2bf(wb.z); t[7] = (short)f2bf(wb.w);
            } else {
#pragma unroll
                for (int j = 0; j < 8; ++j) t[j] = 0;
            }
            Af[ks] = t;
        }

        f32x16 C0, C1;
#pragma unroll
        for (int r = 0; r < 16; ++r) { C0[r] = 0.f; C1[r] = 0.f; }
#pragma unroll
        for (int ks = 0; ks < 3; ++ks) {
            C0 = __builtin_amdgcn_mfma_f32_32x32x16_bf16(Af[ks], Bf1[0][ks], C0, 0, 0, 0);
            C1 = __builtin_amdgcn_mfma_f32_32x32x16_bf16(Af[ks], Bf1[1][ks], C1, 0, 0, 0);
        }

        __syncthreads();
#pragma unroll
        for (int q = 0; q < 2; ++q) {   // rows < 16 only (real channels)
            const int base = 8 * q + 4 * lhi;
            float4 a, c;
            a.x = C0[4 * q]; a.y = C0[4 * q + 1]; a.z = C0[4 * q + 2]; a.w = C0[4 * q + 3];
            c.x = C1[4 * q]; c.y = C1[4 * q + 1]; c.z = C1[4 * q + 2]; c.w = C1[4 * q + 3];
            *(float4*)&y[w64 + l31][base] = a;
            *(float4*)&y[w64 + 32 + l31][base] = c;
        }
        __syncthreads();

        if (valid) {
            float o[16];
#pragma unroll
            for (int c = 0; c < 16; ++c) o[c] = 0.f;
#pragma unroll
            for (int dy = 0; dy < 3; ++dy)
#pragma unroll
                for (int dx = 0; dx < 3; ++dx) {
                    const int tap = dy * 3 + dx;
                    const float* yp = &y[(ily + dy) * HALO + (ilx + dx)][0];
                    float yv[16];
                    *(float4*)&yv[0]  = *(const float4*)(yp);
                    *(float4*)&yv[4]  = *(const float4*)(yp + 4);
                    *(float4*)&yv[8]  = *(const float4*)(yp + 8);
                    *(float4*)&yv[12] = *(const float4*)(yp + 12);
#pragma unroll
                    for (int c = 0; c < 16; ++c)
                        o[c] = fmaf(v_dw[(vt * 16 + c) * 9 + tap], yv[c], o[c]);
                }
#pragma unroll
            for (int c = 0; c < 16; ++c)
                v_buf[((size_t)b * NC_IN + vt * 16 + c) * HW + opix] = o[c];
        }
    }

    __syncthreads();
    for (int i = tid; i < 384; i += 256) atomicAdd(&stats[b * 384 + i], sacc[i]);
}

// ---------------------------------------------------------------------------
// K2: softmax over 6 + fold proj: W2[b][c][dg]
// ---------------------------------------------------------------------------
__global__ __launch_bounds__(256) void softmax_w2_kernel(
    const float* __restrict__ stats, const float* __restrict__ proj_w,
    const float* __restrict__ temperature, float* __restrict__ w2) {
    const int b = blockIdx.x;
    const int tid = threadIdx.x;
    __shared__ float attn[NHEADS * 36];
    const float* sb = stats + b * 384;

    if (tid < 48) {
        const int h = tid / 6, cc = tid % 6;
        float nq = fmaxf(sqrtf(sb[tid]), 1e-12f);
        const float tmp = temperature[h];
        float lo[6];
#pragma unroll
        for (int d = 0; d < 6; ++d) {
            const float nk = fmaxf(sqrtf(sb[48 + h * 6 + d]), 1e-12f);
            lo[d] = sb[96 + h * 36 + cc * 6 + d] / (nq * nk) * tmp;
        }
        float m = lo[0];
#pragma unroll
        for (int d = 1; d < 6; ++d) m = fmaxf(m, lo[d]);
        float s = 0.f;
#pragma unroll
        for (int d = 0; d < 6; ++d) { lo[d] = expf(lo[d] - m); s += lo[d]; }
        const float inv = 1.f / s;
#pragma unroll
        for (int d = 0; d < 6; ++d) attn[h * 36 + cc * 6 + d] = lo[d] * inv;
    }
    __syncthreads();

    for (int idx = tid; idx < 48 * 48; idx += 256) {
        const int c = idx / 48, dg = idx % 48;
        const int h = dg / 6, hd = dg % 6;
        float s = 0.f;
#pragma unroll
        for (int cc = 0; cc < 6; ++cc)
            s = fmaf(proj_w[c * 48 + h * 6 + cc], attn[h * 36 + cc * 6 + hd], s);
        w2[b * 2304 + idx] = s;
    }
}

// ---------------------------------------------------------------------------
// K3: out[b][c][pix] = sum_d W2[b][c][d] * v[b][d][pix]   (2 px / thread)
// ---------------------------------------------------------------------------
__global__ __launch_bounds__(256) void out_kernel(
    const float* __restrict__ v_buf, const float* __restrict__ w2,
    float* __restrict__ out) {
    __shared__ float w[48 * 48];
    const int b = blockIdx.y;
    for (int i = threadIdx.x; i < 48 * 48; i += 256) w[i] = w2[b * 2304 + i];
    __syncthreads();

    const int pixBase = (blockIdx.x * 256 + threadIdx.x) * 2;
    const float* vb = v_buf + (size_t)b * 48 * HW;
    float* ob = out + (size_t)b * 48 * HW;

    float vx[48], vy[48];
#pragma unroll
    for (int d = 0; d < 48; ++d) {
        const float2 t = *reinterpret_cast<const float2*>(&vb[(size_t)d * HW + pixBase]);
        vx[d] = t.x; vy[d] = t.y;
    }
#pragma unroll
    for (int c = 0; c < 48; ++c) {
        float ax = 0.f, ay = 0.f;
#pragma unroll
        for (int d4 = 0; d4 < 12; ++d4) {
            const float4 ww = *reinterpret_cast<const float4*>(&w[c * 48 + d4 * 4]);
            ax = fmaf(ww.x, vx[d4 * 4 + 0], ax); ay = fmaf(ww.x, vy[d4 * 4 + 0], ay);
            ax = fmaf(ww.y, vx[d4 * 4 + 1], ax); ay = fmaf(ww.y, vy[d4 * 4 + 1], ay);
            ax = fmaf(ww.z, vx[d4 * 4 + 2], ax); ay = fmaf(ww.z, vy[d4 * 4 + 2], ay);
            ax = fmaf(ww.w, vx[d4 * 4 + 3], ax); ay = fmaf(ww.w, vy[d4 * 4 + 3], ay);
        }
        float2 r; r.x = ax; r.y = ay;
        *reinterpret_cast<float2*>(&ob[(size_t)c * HW + pixBase]) = r;
    }
}

// ---------------------------------------------------------------------------
extern "C" void kernel_launch(void* const* d_in, const int* in_sizes, int n_in,
                              void* d_out, int out_size, void* d_ws, size_t ws_size,
                              hipStream_t stream) {
    const float* fea0 = (const float*)d_in[0];
    const float* fea1 = (const float*)d_in[1];
    const float* qk_w = (const float*)d_in[2];
    const float* qk_dw = (const float*)d_in[3];
    const float* v_w = (const float*)d_in[4];
    const float* v_dw = (const float*)d_in[5];
    const float* proj_w = (const float*)d_in[6];
    const float* temperature = (const float*)d_in[7];
    float* out = (float*)d_out;

    char* ws = (char*)d_ws;
    const size_t V_BYTES = (size_t)NB * NC_IN * HW * sizeof(float);  // 50,331,648
    const size_t ST_BYTES = (size_t)NB * 384 * sizeof(float);
    float* v_buf = (float*)ws;
    float* stats = (float*)(ws + V_BYTES);
    float* w2 = (float*)(ws + V_BYTES + ST_BYTES);

    hipMemsetAsync(stats, 0, ST_BYTES, stream);

    conv_all_kernel<<<dim3(NTILES, NB), 256, 0, stream>>>(
        fea0, fea1, qk_w, qk_dw, v_w, v_dw, v_buf, stats);
    softmax_w2_kernel<<<NB, 256, 0, stream>>>(stats, proj_w, temperature, w2);
    out_kernel<<<dim3(HW / 512, NB), 256, 0, stream>>>(v_buf, w2, out);
}

// Round 4
// 142.455 us; speedup vs baseline: 1.2415x; 1.2415x over previous
//
#include <hip/hip_runtime.h>
#include <cstddef>

#define IMG 256
#define HW 65536
#define NB 4
#define NC_IN 48
#define NHEADS 8
#define TILE 14
#define HALO 16
#define NT 19          // ceil(256/14)
#define NTILES (NT*NT) // 361
#define OHALO 18
#define OHP (OHALO*OHALO)  // 324

typedef short bf16x8 __attribute__((ext_vector_type(8)));
typedef float f32x4 __attribute__((ext_vector_type(4)));
typedef float f32x16 __attribute__((ext_vector_type(16)));

__device__ __forceinline__ unsigned short f2bf(float f) {
    unsigned int x = __float_as_uint(f);
    unsigned int r = (x + 0x7fffu + ((x >> 16) & 1u)) >> 16;
    return (unsigned short)r;
}

// bijective XCD-contiguous remap (m204): consecutive output ids land on one XCD
__device__ __forceinline__ int xcd_map(int bid, int nwg) {
    const int q = nwg >> 3, r = nwg & 7;
    const int x = bid & 7, i = bid >> 3;
    return (x < r ? x * (q + 1) : r * (q + 1) + (x - r) * q) + i;
}

// ---------------------------------------------------------------------------
// K1: qk path. 16x16 halo tile (14x14 interior), 4 m-tiles (2 heads each).
//  conv1x1 via mfma 32x32x16 bf16 -> y LDS [256][28] f32 -> dwconv3x3 VALU ->
//  Gram/norm stats via 16x16x32 MFMA (head-sequential staging in sg) -> atomics.
// stats per b (384 f32): [0..47]=qq(h*6+c), [48..95]=kk, [96..]=h*36+cc*6+d
// LDS: y 28672 + sg 9216 + sacc 1536 = 39424 B -> 4 blocks/CU
// ---------------------------------------------------------------------------
__global__ __launch_bounds__(256) void fused_qk_stats_kernel(
    const float* __restrict__ fea0, const float* __restrict__ qk_w,
    const float* __restrict__ qk_dw, float* __restrict__ stats) {
    __shared__ float y[256][28];
    __shared__ __align__(16) unsigned short sg[4][16][72];
    __shared__ float sacc[384];

    const int tid = threadIdx.x;
    const int b = blockIdx.y;
    const int tile = xcd_map(blockIdx.x, NTILES);
    const int tx = tile % NT, ty = tile / NT;
    const int wave = tid >> 6, lane = tid & 63;
    const int l31 = lane & 31, lhi = lane >> 5;
    const int w64 = wave * 64;

    for (int i = tid; i < 384; i += 256) sacc[i] = 0.f;

    const float* fb = fea0 + (size_t)b * NC_IN * HW;

    // B fragments: input pixels (held in registers for all m-tiles)
    bf16x8 Bf[2][3];
#pragma unroll
    for (int n = 0; n < 2; ++n) {
        const int px = w64 + n * 32 + l31;
        const int hx = px & 15, hy = px >> 4;
        const int gx = tx * TILE + hx - 1, gy = ty * TILE + hy - 1;
        const bool inb = ((unsigned)gx < (unsigned)IMG) && ((unsigned)gy < (unsigned)IMG);
        const int pix = inb ? (gy * IMG + gx) : 0;
#pragma unroll
        for (int ks = 0; ks < 3; ++ks) {
            const int ch0 = ks * 16 + lhi * 8;
            bf16x8 t;
#pragma unroll
            for (int j = 0; j < 8; ++j) {
                const float x = inb ? fb[(size_t)(ch0 + j) * HW + pix] : 0.f;
                t[j] = (short)f2bf(x);
            }
            Bf[n][ks] = t;
        }
    }

    const int ilx = tid % TILE, ily = tid / TILE;
    const int gxi = tx * TILE + ilx, gyi = ty * TILE + ily;
    const bool valid = (tid < TILE * TILE) && (gxi < IMG) && (gyi < IMG);

    const int fr = lane & 15, fg = lane >> 4;

    for (int m = 0; m < 4; ++m) {
        const int h0 = 2 * m;

        // A fragments: permuted+padded weight rows (16/head: q6 k6 pad4)
        const int sub = l31 & 15;
        const int hh_ = h0 + (l31 >> 4);
        const bool wok = sub < 12;
        const int wr = (sub < 6) ? (hh_ * 6 + sub) : (48 + hh_ * 6 + (sub - 6));
        bf16x8 Af[3];
#pragma unroll
        for (int ks = 0; ks < 3; ++ks) {
            const int k0 = ks * 16 + lhi * 8;
            bf16x8 t;
            if (wok) {
                const float4 wa = *(const float4*)&qk_w[wr * 48 + k0];
                const float4 wb = *(const float4*)&qk_w[wr * 48 + k0 + 4];
                t[0] = (short)f2bf(wa.x); t[1] = (short)f2bf(wa.y);
                t[2] = (short)f2bf(wa.z); t[3] = (short)f2bf(wa.w);
                t[4] = (short)f2bf(wb.x); t[5] = (short)f2bf(wb.y);
                t[6] = (short)f2bf(wb.z); t[7] = (short)f2bf(wb.w);
            } else {
#pragma unroll
                for (int j = 0; j < 8; ++j) t[j] = 0;
            }
            Af[ks] = t;
        }

        f32x16 C0, C1;
#pragma unroll
        for (int r = 0; r < 16; ++r) { C0[r] = 0.f; C1[r] = 0.f; }
#pragma unroll
        for (int ks = 0; ks < 3; ++ks) {
            C0 = __builtin_amdgcn_mfma_f32_32x32x16_bf16(Af[ks], Bf[0][ks], C0, 0, 0, 0);
            C1 = __builtin_amdgcn_mfma_f32_32x32x16_bf16(Af[ks], Bf[1][ks], C1, 0, 0, 0);
        }

        __syncthreads();  // previous tile's y reads complete
        // float4 row-quad writes: rows 4q..4q+3 are consecutive channels
#pragma unroll
        for (int q = 0; q < 4; ++q) {
            const int base = 8 * q + 4 * lhi;
            const int rsub = base & 15;
            if (rsub < 12) {
                const int ych = (base >> 4) * 12 + rsub;
                float4 a, c;
                a.x = C0[4 * q]; a.y = C0[4 * q + 1]; a.z = C0[4 * q + 2]; a.w = C0[4 * q + 3];
                c.x = C1[4 * q]; c.y = C1[4 * q + 1]; c.z = C1[4 * q + 2]; c.w = C1[4 * q + 3];
                *(float4*)&y[w64 + l31][ych] = a;
                *(float4*)&y[w64 + 32 + l31][ych] = c;
            }
        }
        __syncthreads();

        // depthwise 3x3 on 24 channels (2 heads)
        float qk2[24];
#pragma unroll
        for (int c = 0; c < 24; ++c) qk2[c] = 0.f;
        if (valid) {
#pragma unroll
            for (int dy = 0; dy < 3; ++dy)
#pragma unroll
                for (int dx = 0; dx < 3; ++dx) {
                    const int tap = dy * 3 + dx;
                    const float* yp = &y[(ily + dy) * HALO + (ilx + dx)][0];
                    float yv[24];
                    *(float4*)&yv[0]  = *(const float4*)(yp);
                    *(float4*)&yv[4]  = *(const float4*)(yp + 4);
                    *(float4*)&yv[8]  = *(const float4*)(yp + 8);
                    *(float4*)&yv[12] = *(const float4*)(yp + 12);
                    *(float4*)&yv[16] = *(const float4*)(yp + 16);
                    *(float4*)&yv[20] = *(const float4*)(yp + 20);
#pragma unroll
                    for (int c = 0; c < 24; ++c) {
                        const int hh = h0 + (c >= 12);
                        const int s = c - (c >= 12 ? 12 : 0);
                        const int dr = (s < 6) ? (hh * 6 + s) : (48 + hh * 6 + (s - 6));
                        qk2[c] = fmaf(qk_dw[dr * 9 + tap], yv[c], qk2[c]);
                    }
                }
        }

        // Gram stats via MFMA, head-sequential through one 16-row staging buf
#pragma unroll
        for (int hh = 0; hh < 2; ++hh) {
#pragma unroll
            for (int c = 0; c < 12; ++c) sg[wave][c][lane] = f2bf(qk2[hh * 12 + c]);
            asm volatile("s_waitcnt lgkmcnt(0)" ::: "memory");
            __builtin_amdgcn_sched_barrier(0);
            const bf16x8 a0 = *(const bf16x8*)&sg[wave][fr][fg * 8];
            const bf16x8 a1 = *(const bf16x8*)&sg[wave][fr][32 + fg * 8];
            asm volatile("s_waitcnt lgkmcnt(0)" ::: "memory");
            __builtin_amdgcn_sched_barrier(0);
            f32x4 c4 = {0.f, 0.f, 0.f, 0.f};
            c4 = __builtin_amdgcn_mfma_f32_16x16x32_bf16(a0, a0, c4, 0, 0, 0);
            c4 = __builtin_amdgcn_mfma_f32_16x16x32_bf16(a1, a1, c4, 0, 0, 0);
            const int h = h0 + hh;
#pragma unroll
            for (int r = 0; r < 4; ++r) {
                const int crow = fg * 4 + r;
                const float vv = c4[r];
                if (crow < 6) {
                    if (fr == crow) atomicAdd(&sacc[h * 6 + crow], vv);
                    else if (fr >= 6 && fr < 12)
                        atomicAdd(&sacc[96 + h * 36 + crow * 6 + (fr - 6)], vv);
                } else if (crow < 12 && fr == crow) {
                    atomicAdd(&sacc[48 + h * 6 + (crow - 6)], vv);
                }
            }
        }
    }

    __syncthreads();
    for (int i = tid; i < 384; i += 256) atomicAdd(&stats[b * 384 + i], sacc[i]);
}

// ---------------------------------------------------------------------------
// K2: softmax(6) -> W2[c][d] = proj . blockdiag(attn) -> combined 3x3 weights
//     cw[tap][c][e] = sum_d W2[c][d] * v_w[d][e] * v_dw[d][tap]  (bf16)
// ---------------------------------------------------------------------------
__global__ __launch_bounds__(256) void softmax_w2_cw_kernel(
    const float* __restrict__ stats, const float* __restrict__ proj_w,
    const float* __restrict__ temperature, const float* __restrict__ v_w,
    const float* __restrict__ v_dw, unsigned short* __restrict__ cwb) {
    const int b = blockIdx.x;
    const int tid = threadIdx.x;
    __shared__ float attn[NHEADS * 36];
    __shared__ float W2s[48 * 48];
    const float* sb = stats + b * 384;

    if (tid < 48) {
        const int h = tid / 6, cc = tid % 6;
        float nq = fmaxf(sqrtf(sb[tid]), 1e-12f);
        const float tmp = temperature[h];
        float lo[6];
#pragma unroll
        for (int d = 0; d < 6; ++d) {
            const float nk = fmaxf(sqrtf(sb[48 + h * 6 + d]), 1e-12f);
            lo[d] = sb[96 + h * 36 + cc * 6 + d] / (nq * nk) * tmp;
        }
        float m = lo[0];
#pragma unroll
        for (int d = 1; d < 6; ++d) m = fmaxf(m, lo[d]);
        float s = 0.f;
#pragma unroll
        for (int d = 0; d < 6; ++d) { lo[d] = expf(lo[d] - m); s += lo[d]; }
        const float inv = 1.f / s;
#pragma unroll
        for (int d = 0; d < 6; ++d) attn[h * 36 + cc * 6 + d] = lo[d] * inv;
    }
    __syncthreads();

    for (int idx = tid; idx < 48 * 48; idx += 256) {
        const int c = idx / 48, dg = idx % 48;
        const int h = dg / 6, hd = dg % 6;
        float s = 0.f;
#pragma unroll
        for (int cc = 0; cc < 6; ++cc)
            s = fmaf(proj_w[c * 48 + h * 6 + cc], attn[h * 36 + cc * 6 + hd], s);
        W2s[idx] = s;
    }
    __syncthreads();

    // 2304 (c,e) pairs = 9 per thread; each folds over d with 9 taps
    for (int p = 0; p < 9; ++p) {
        const int pair = p * 256 + tid;
        const int c = pair / 48, e = pair % 48;
        float acc[9];
#pragma unroll
        for (int t = 0; t < 9; ++t) acc[t] = 0.f;
        for (int d = 0; d < 48; ++d) {
            const float wv = W2s[c * 48 + d] * v_w[d * 48 + e];
#pragma unroll
            for (int t = 0; t < 9; ++t)
                acc[t] = fmaf(wv, v_dw[d * 9 + t], acc[t]);
        }
#pragma unroll
        for (int t = 0; t < 9; ++t)
            cwb[(size_t)b * 20736 + (size_t)(t * 48 + c) * 48 + e] = f2bf(acc[t]);
    }
}

// ---------------------------------------------------------------------------
// K3: out = cw (*) fea1 : full 3x3 conv 48->48 via MFMA.
//  16x16 output tile, 18x18 halo staged bf16 in LDS [324][56] (36288 B).
//  Per wave: 2 m-tiles x 2 n-halves x 9 taps x 3 k-steps = 108 mfma 32x32x16.
// ---------------------------------------------------------------------------
__global__ __launch_bounds__(256) void conv3x3_out_kernel(
    const float* __restrict__ fea1, const unsigned short* __restrict__ cwb,
    float* __restrict__ out) {
    __shared__ __align__(16) unsigned short xs[OHP][56];

    const int tid = threadIdx.x;
    const int b = blockIdx.y;
    const int tile = xcd_map(blockIdx.x, 256);
    const int tx = tile & 15, ty = tile >> 4;
    const float* fb = fea1 + (size_t)b * NC_IN * HW;

    // stage 18x18 halo, 48 ch, bf16
    for (int hp = tid; hp < OHP; hp += 256) {
        const int hx = hp % OHALO, hy = hp / OHALO;
        const int gx = tx * 16 + hx - 1, gy = ty * 16 + hy - 1;
        const bool inb = ((unsigned)gx < (unsigned)IMG) && ((unsigned)gy < (unsigned)IMG);
        const int pix = inb ? (gy * IMG + gx) : 0;
#pragma unroll
        for (int j = 0; j < 6; ++j) {
            bf16x8 t;
#pragma unroll
            for (int c = 0; c < 8; ++c) {
                const float v = inb ? fb[(size_t)(j * 8 + c) * HW + pix] : 0.f;
                t[c] = (short)f2bf(v);
            }
            *(bf16x8*)&xs[hp][j * 8] = t;
        }
    }
    __syncthreads();

    const int wave = tid >> 6, lane = tid & 63;
    const int l31 = lane & 31, lhi = lane >> 5;
    const int opx0 = wave * 64 + l31, opx1 = opx0 + 32;
    const int r0 = (opx0 >> 4) * OHALO + (opx0 & 15);
    const int r1 = (opx1 >> 4) * OHALO + (opx1 & 15);
    const unsigned short* cb = cwb + (size_t)b * 20736;
    const bool m1ok = l31 < 16;

    f32x16 C00, C01, C10, C11;
#pragma unroll
    for (int r = 0; r < 16; ++r) { C00[r] = 0.f; C01[r] = 0.f; C10[r] = 0.f; C11[r] = 0.f; }

#pragma unroll
    for (int dy = 0; dy < 3; ++dy)
#pragma unroll
        for (int dx = 0; dx < 3; ++dx) {
            const int t9 = dy * 3 + dx;
            const int hoff = dy * OHALO + dx;
#pragma unroll
            for (int ks = 0; ks < 3; ++ks) {
                const int kb = ks * 16 + lhi * 8;
                const bf16x8 a0 = *(const bf16x8*)&cb[(size_t)(t9 * 48 + l31) * 48 + kb];
                bf16x8 a1;
#pragma unroll
                for (int j = 0; j < 8; ++j) a1[j] = 0;
                if (m1ok) a1 = *(const bf16x8*)&cb[(size_t)(t9 * 48 + 32 + l31) * 48 + kb];
                const bf16x8 b0 = *(const bf16x8*)&xs[r0 + hoff][kb];
                const bf16x8 b1 = *(const bf16x8*)&xs[r1 + hoff][kb];
                C00 = __builtin_amdgcn_mfma_f32_32x32x16_bf16(a0, b0, C00, 0, 0, 0);
                C01 = __builtin_amdgcn_mfma_f32_32x32x16_bf16(a0, b1, C01, 0, 0, 0);
                C10 = __builtin_amdgcn_mfma_f32_32x32x16_bf16(a1, b0, C10, 0, 0, 0);
                C11 = __builtin_amdgcn_mfma_f32_32x32x16_bf16(a1, b1, C11, 0, 0, 0);
            }
        }

    float* ob = out + (size_t)b * NC_IN * HW;
    const int g0 = (ty * 16 + (opx0 >> 4)) * IMG + tx * 16 + (opx0 & 15);
    const int g1 = (ty * 16 + (opx1 >> 4)) * IMG + tx * 16 + (opx1 & 15);
#pragma unroll
    for (int r = 0; r < 16; ++r) {
        const int row = (r & 3) + 8 * (r >> 2) + 4 * lhi;
        ob[(size_t)row * HW + g0] = C00[r];
        ob[(size_t)row * HW + g1] = C01[r];
        const int row1 = 32 + row;
        if (row1 < 48) {
            ob[(size_t)row1 * HW + g0] = C10[r];
            ob[(size_t)row1 * HW + g1] = C11[r];
        }
    }
}

// ---------------------------------------------------------------------------
extern "C" void kernel_launch(void* const* d_in, const int* in_sizes, int n_in,
                              void* d_out, int out_size, void* d_ws, size_t ws_size,
                              hipStream_t stream) {
    const float* fea0 = (const float*)d_in[0];
    const float* fea1 = (const float*)d_in[1];
    const float* qk_w = (const float*)d_in[2];
    const float* qk_dw = (const float*)d_in[3];
    const float* v_w = (const float*)d_in[4];
    const float* v_dw = (const float*)d_in[5];
    const float* proj_w = (const float*)d_in[6];
    const float* temperature = (const float*)d_in[7];
    float* out = (float*)d_out;

    char* ws = (char*)d_ws;
    const size_t ST_BYTES = (size_t)NB * 384 * sizeof(float);     // 6144
    float* stats = (float*)ws;
    unsigned short* cwb = (unsigned short*)(ws + 8192);           // 4*9*48*48*2 B

    hipMemsetAsync(stats, 0, ST_BYTES, stream);

    fused_qk_stats_kernel<<<dim3(NTILES, NB), 256, 0, stream>>>(fea0, qk_w, qk_dw, stats);
    softmax_w2_cw_kernel<<<NB, 256, 0, stream>>>(stats, proj_w, temperature, v_w, v_dw, cwb);
    conv3x3_out_kernel<<<dim3(256, NB), 256, 0, stream>>>(fea1, cwb, out);
}

// Round 5
// 129.463 us; speedup vs baseline: 1.3661x; 1.1003x over previous
//
#include <hip/hip_runtime.h>
#include <cstddef>

#define IMG 256
#define HW 65536
#define NB 4
#define NC_IN 48
#define NHEADS 8
#define OHALO 18
#define OHP (OHALO*OHALO)  // 324

typedef short bf16x8 __attribute__((ext_vector_type(8)));
typedef float f32x4 __attribute__((ext_vector_type(4)));
typedef float f32x16 __attribute__((ext_vector_type(16)));

__device__ __forceinline__ unsigned short f2bf(float f) {
    unsigned int x = __float_as_uint(f);
    unsigned int r = (x + 0x7fffu + ((x >> 16) & 1u)) >> 16;
    return (unsigned short)r;
}

// bijective XCD-contiguous remap (m204)
__device__ __forceinline__ int xcd_map(int bid, int nwg) {
    const int q = nwg >> 3, r = nwg & 7;
    const int x = bid & 7, i = bid >> 3;
    return (x < r ? x * (q + 1) : r * (q + 1) + (x - r) * q) + i;
}

// ---------------------------------------------------------------------------
// K0: combined qk 3x3 weights, permuted+padded M layout.
//  slot s in [0,128): head=s>>4, sub=s&15 (q6 k6 pad4)
//  qcw[tap][s][e] = qk_dw[row,tap] * qk_w[row,e], bf16. 9*128*48 = 55296 elems.
// ---------------------------------------------------------------------------
__global__ __launch_bounds__(256) void prep_qcw_kernel(
    const float* __restrict__ qk_w, const float* __restrict__ qk_dw,
    unsigned short* __restrict__ qcwb) {
    const int idx = blockIdx.x * 256 + threadIdx.x;
    if (idx >= 9 * 128 * 48) return;
    const int e = idx % 48;
    const int s = (idx / 48) & 127;
    const int tap = idx / (48 * 128);
    const int head = s >> 4, sub = s & 15;
    float v = 0.f;
    if (sub < 12) {
        const int row = (sub < 6) ? (head * 6 + sub) : (48 + head * 6 + (sub - 6));
        v = qk_dw[row * 9 + tap] * qk_w[row * 48 + e];
    }
    qcwb[idx] = f2bf(v);
}

// ---------------------------------------------------------------------------
// K1: qk path as ONE full 3x3 conv via MFMA + in-register Gram stats.
//  16x16 exact output tile, 18x18 halo staged bf16 in xs[324][56].
//  2 m-pairs x 9 taps x 3 ks x (2m x 2n MFMA 32x32x16) = 216 MFMA/wave.
//  Stats per m-tile (2 heads): stage C as bf16 [12ch x 64px] per wave,
//  Gram via 16x16x32 MFMA (A=B -> symmetric, layout-swap-immune), LDS atomics.
// stats per b (384 f32): [0..47]=qq(h*6+c), [48..95]=kk, [96..]=h*36+cc*6+d
// LDS: 36288 + 9216 + 1536 = 47040 B -> 3 blocks/CU
// ---------------------------------------------------------------------------
__global__ __launch_bounds__(256, 3) void fused_qk_stats_kernel(
    const float* __restrict__ fea0, const unsigned short* __restrict__ qcwb,
    float* __restrict__ stats) {
    __shared__ __align__(16) unsigned short xs[OHP][56];
    __shared__ __align__(16) unsigned short sg[4][16][72];
    __shared__ float sacc[384];

    const int tid = threadIdx.x;
    const int b = blockIdx.y;
    const int tile = xcd_map(blockIdx.x, 256);
    const int tx = tile & 15, ty = tile >> 4;
    const float* fb = fea0 + (size_t)b * NC_IN * HW;

    for (int i = tid; i < 384; i += 256) sacc[i] = 0.f;

    // stage 18x18 halo, 48 ch, bf16
    for (int hp = tid; hp < OHP; hp += 256) {
        const int hx = hp % OHALO, hy = hp / OHALO;
        const int gx = tx * 16 + hx - 1, gy = ty * 16 + hy - 1;
        const bool inb = ((unsigned)gx < (unsigned)IMG) && ((unsigned)gy < (unsigned)IMG);
        const int pix = inb ? (gy * IMG + gx) : 0;
#pragma unroll
        for (int j = 0; j < 6; ++j) {
            bf16x8 t;
#pragma unroll
            for (int c = 0; c < 8; ++c) {
                const float v = inb ? fb[(size_t)(j * 8 + c) * HW + pix] : 0.f;
                t[c] = (short)f2bf(v);
            }
            *(bf16x8*)&xs[hp][j * 8] = t;
        }
    }
    __syncthreads();

    const int wave = tid >> 6, lane = tid & 63;
    const int l31 = lane & 31, lhi = lane >> 5;
    const int opx0 = wave * 64 + l31, opx1 = opx0 + 32;
    const int r0 = (opx0 >> 4) * OHALO + (opx0 & 15);
    const int r1 = (opx1 >> 4) * OHALO + (opx1 & 15);
    const int fr = lane & 15, fg = lane >> 4;

    // stats emit for one m-tile's C pair (rows=2 heads x (q6 k6 pad4), cols=64 px)
#define DO_STATS(CA, CB, hbase)                                                   \
    {                                                                             \
        _Pragma("unroll")                                                         \
        for (int hh = 0; hh < 2; ++hh) {                                          \
            _Pragma("unroll")                                                     \
            for (int rq = 0; rq < 2; ++rq) {                                      \
                if (!(rq && lhi)) {                                               \
                    _Pragma("unroll")                                             \
                    for (int j = 0; j < 4; ++j) {                                 \
                        const int sub = j + 8 * rq + 4 * lhi;                     \
                        sg[wave][sub][l31] = f2bf(CA[hh * 8 + rq * 4 + j]);       \
                        sg[wave][sub][32 + l31] = f2bf(CB[hh * 8 + rq * 4 + j]);  \
                    }                                                             \
                }                                                                 \
            }                                                                     \
            asm volatile("s_waitcnt lgkmcnt(0)" ::: "memory");                    \
            __builtin_amdgcn_sched_barrier(0);                                    \
            const bf16x8 a0 = *(const bf16x8*)&sg[wave][fr][fg * 8];              \
            const bf16x8 a1 = *(const bf16x8*)&sg[wave][fr][32 + fg * 8];         \
            asm volatile("s_waitcnt lgkmcnt(0)" ::: "memory");                    \
            __builtin_amdgcn_sched_barrier(0);                                    \
            f32x4 c4 = {0.f, 0.f, 0.f, 0.f};                                      \
            c4 = __builtin_amdgcn_mfma_f32_16x16x32_bf16(a0, a0, c4, 0, 0, 0);    \
            c4 = __builtin_amdgcn_mfma_f32_16x16x32_bf16(a1, a1, c4, 0, 0, 0);    \
            const int h = (hbase) + hh;                                           \
            _Pragma("unroll")                                                     \
            for (int r = 0; r < 4; ++r) {                                         \
                const int crow = fg * 4 + r;                                      \
                const float vv = c4[r];                                           \
                if (crow < 6) {                                                   \
                    if (fr == crow) atomicAdd(&sacc[h * 6 + crow], vv);           \
                    else if (fr >= 6 && fr < 12)                                  \
                        atomicAdd(&sacc[96 + h * 36 + crow * 6 + (fr - 6)], vv);  \
                } else if (crow < 12 && fr == crow) {                             \
                    atomicAdd(&sacc[48 + h * 6 + (crow - 6)], vv);                \
                }                                                                 \
            }                                                                     \
        }                                                                         \
    }

#pragma unroll
    for (int p = 0; p < 2; ++p) {
        f32x16 C00, C01, C10, C11;
#pragma unroll
        for (int r = 0; r < 16; ++r) { C00[r] = 0.f; C01[r] = 0.f; C10[r] = 0.f; C11[r] = 0.f; }

#pragma unroll
        for (int t9 = 0; t9 < 9; ++t9) {
            const int hoff = (t9 / 3) * OHALO + (t9 % 3);
#pragma unroll
            for (int ks = 0; ks < 3; ++ks) {
                const int kb = ks * 16 + lhi * 8;
                const bf16x8 b0 = *(const bf16x8*)&xs[r0 + hoff][kb];
                const bf16x8 b1 = *(const bf16x8*)&xs[r1 + hoff][kb];
                const bf16x8 a0 = *(const bf16x8*)&qcwb[((size_t)t9 * 128 + p * 64 + l31) * 48 + kb];
                const bf16x8 a1 = *(const bf16x8*)&qcwb[((size_t)t9 * 128 + p * 64 + 32 + l31) * 48 + kb];
                C00 = __builtin_amdgcn_mfma_f32_32x32x16_bf16(a0, b0, C00, 0, 0, 0);
                C01 = __builtin_amdgcn_mfma_f32_32x32x16_bf16(a0, b1, C01, 0, 0, 0);
                C10 = __builtin_amdgcn_mfma_f32_32x32x16_bf16(a1, b0, C10, 0, 0, 0);
                C11 = __builtin_amdgcn_mfma_f32_32x32x16_bf16(a1, b1, C11, 0, 0, 0);
            }
        }

        DO_STATS(C00, C01, p * 4 + 0)
        DO_STATS(C10, C11, p * 4 + 2)
    }
#undef DO_STATS

    __syncthreads();
    for (int i = tid; i < 384; i += 256) atomicAdd(&stats[b * 384 + i], sacc[i]);
}

// ---------------------------------------------------------------------------
// K2: softmax(6) -> W2 = proj . blockdiag(attn) -> combined v-side 3x3 weights
//     cw[tap][c][e] = sum_d W2[c][d] * v_w[d][e] * v_dw[d][tap]  (bf16)
// ---------------------------------------------------------------------------
__global__ __launch_bounds__(256) void softmax_w2_cw_kernel(
    const float* __restrict__ stats, const float* __restrict__ proj_w,
    const float* __restrict__ temperature, const float* __restrict__ v_w,
    const float* __restrict__ v_dw, unsigned short* __restrict__ cwb) {
    const int b = blockIdx.x;
    const int tid = threadIdx.x;
    __shared__ float attn[NHEADS * 36];
    __shared__ float W2s[48 * 48];
    const float* sb = stats + b * 384;

    if (tid < 48) {
        const int h = tid / 6, cc = tid % 6;
        float nq = fmaxf(sqrtf(sb[tid]), 1e-12f);
        const float tmp = temperature[h];
        float lo[6];
#pragma unroll
        for (int d = 0; d < 6; ++d) {
            const float nk = fmaxf(sqrtf(sb[48 + h * 6 + d]), 1e-12f);
            lo[d] = sb[96 + h * 36 + cc * 6 + d] / (nq * nk) * tmp;
        }
        float m = lo[0];
#pragma unroll
        for (int d = 1; d < 6; ++d) m = fmaxf(m, lo[d]);
        float s = 0.f;
#pragma unroll
        for (int d = 0; d < 6; ++d) { lo[d] = expf(lo[d] - m); s += lo[d]; }
        const float inv = 1.f / s;
#pragma unroll
        for (int d = 0; d < 6; ++d) attn[h * 36 + cc * 6 + d] = lo[d] * inv;
    }
    __syncthreads();

    for (int idx = tid; idx < 48 * 48; idx += 256) {
        const int c = idx / 48, dg = idx % 48;
        const int h = dg / 6, hd = dg % 6;
        float s = 0.f;
#pragma unroll
        for (int cc = 0; cc < 6; ++cc)
            s = fmaf(proj_w[c * 48 + h * 6 + cc], attn[h * 36 + cc * 6 + hd], s);
        W2s[idx] = s;
    }
    __syncthreads();

    for (int p = 0; p < 9; ++p) {
        const int pair = p * 256 + tid;
        const int c = pair / 48, e = pair % 48;
        float acc[9];
#pragma unroll
        for (int t = 0; t < 9; ++t) acc[t] = 0.f;
        for (int d = 0; d < 48; ++d) {
            const float wv = W2s[c * 48 + d] * v_w[d * 48 + e];
#pragma unroll
            for (int t = 0; t < 9; ++t)
                acc[t] = fmaf(wv, v_dw[d * 9 + t], acc[t]);
        }
#pragma unroll
        for (int t = 0; t < 9; ++t)
            cwb[(size_t)b * 20736 + (size_t)(t * 48 + c) * 48 + e] = f2bf(acc[t]);
    }
}

// ---------------------------------------------------------------------------
// K3: out = cw (*) fea1 : full 3x3 conv 48->48 via MFMA.
// ---------------------------------------------------------------------------
__global__ __launch_bounds__(256) void conv3x3_out_kernel(
    const float* __restrict__ fea1, const unsigned short* __restrict__ cwb,
    float* __restrict__ out) {
    __shared__ __align__(16) unsigned short xs[OHP][56];

    const int tid = threadIdx.x;
    const int b = blockIdx.y;
    const int tile = xcd_map(blockIdx.x, 256);
    const int tx = tile & 15, ty = tile >> 4;
    const float* fb = fea1 + (size_t)b * NC_IN * HW;

    for (int hp = tid; hp < OHP; hp += 256) {
        const int hx = hp % OHALO, hy = hp / OHALO;
        const int gx = tx * 16 + hx - 1, gy = ty * 16 + hy - 1;
        const bool inb = ((unsigned)gx < (unsigned)IMG) && ((unsigned)gy < (unsigned)IMG);
        const int pix = inb ? (gy * IMG + gx) : 0;
#pragma unroll
        for (int j = 0; j < 6; ++j) {
            bf16x8 t;
#pragma unroll
            for (int c = 0; c < 8; ++c) {
                const float v = inb ? fb[(size_t)(j * 8 + c) * HW + pix] : 0.f;
                t[c] = (short)f2bf(v);
            }
            *(bf16x8*)&xs[hp][j * 8] = t;
        }
    }
    __syncthreads();

    const int wave = tid >> 6, lane = tid & 63;
    const int l31 = lane & 31, lhi = lane >> 5;
    const int opx0 = wave * 64 + l31, opx1 = opx0 + 32;
    const int r0 = (opx0 >> 4) * OHALO + (opx0 & 15);
    const int r1 = (opx1 >> 4) * OHALO + (opx1 & 15);
    const unsigned short* cb = cwb + (size_t)b * 20736;
    const bool m1ok = l31 < 16;

    f32x16 C00, C01, C10, C11;
#pragma unroll
    for (int r = 0; r < 16; ++r) { C00[r] = 0.f; C01[r] = 0.f; C10[r] = 0.f; C11[r] = 0.f; }

#pragma unroll
    for (int dy = 0; dy < 3; ++dy)
#pragma unroll
        for (int dx = 0; dx < 3; ++dx) {
            const int t9 = dy * 3 + dx;
            const int hoff = dy * OHALO + dx;
#pragma unroll
            for (int ks = 0; ks < 3; ++ks) {
                const int kb = ks * 16 + lhi * 8;
                const bf16x8 a0 = *(const bf16x8*)&cb[(size_t)(t9 * 48 + l31) * 48 + kb];
                bf16x8 a1;
#pragma unroll
                for (int j = 0; j < 8; ++j) a1[j] = 0;
                if (m1ok) a1 = *(const bf16x8*)&cb[(size_t)(t9 * 48 + 32 + l31) * 48 + kb];
                const bf16x8 b0 = *(const bf16x8*)&xs[r0 + hoff][kb];
                const bf16x8 b1 = *(const bf16x8*)&xs[r1 + hoff][kb];
                C00 = __builtin_amdgcn_mfma_f32_32x32x16_bf16(a0, b0, C00, 0, 0, 0);
                C01 = __builtin_amdgcn_mfma_f32_32x32x16_bf16(a0, b1, C01, 0, 0, 0);
                C10 = __builtin_amdgcn_mfma_f32_32x32x16_bf16(a1, b0, C10, 0, 0, 0);
                C11 = __builtin_amdgcn_mfma_f32_32x32x16_bf16(a1, b1, C11, 0, 0, 0);
            }
        }

    float* ob = out + (size_t)b * NC_IN * HW;
    const int g0 = (ty * 16 + (opx0 >> 4)) * IMG + tx * 16 + (opx0 & 15);
    const int g1 = (ty * 16 + (opx1 >> 4)) * IMG + tx * 16 + (opx1 & 15);
#pragma unroll
    for (int r = 0; r < 16; ++r) {
        const int row = (r & 3) + 8 * (r >> 2) + 4 * lhi;
        ob[(size_t)row * HW + g0] = C00[r];
        ob[(size_t)row * HW + g1] = C01[r];
        const int row1 = 32 + row;
        if (row1 < 48) {
            ob[(size_t)row1 * HW + g0] = C10[r];
            ob[(size_t)row1 * HW + g1] = C11[r];
        }
    }
}

// ---------------------------------------------------------------------------
extern "C" void kernel_launch(void* const* d_in, const int* in_sizes, int n_in,
                              void* d_out, int out_size, void* d_ws, size_t ws_size,
                              hipStream_t stream) {
    const float* fea0 = (const float*)d_in[0];
    const float* fea1 = (const float*)d_in[1];
    const float* qk_w = (const float*)d_in[2];
    const float* qk_dw = (const float*)d_in[3];
    const float* v_w = (const float*)d_in[4];
    const float* v_dw = (const float*)d_in[5];
    const float* proj_w = (const float*)d_in[6];
    const float* temperature = (const float*)d_in[7];
    float* out = (float*)d_out;

    char* ws = (char*)d_ws;
    float* stats = (float*)ws;                                    // 6144 B
    unsigned short* cwb = (unsigned short*)(ws + 8192);           // 165888 B
    unsigned short* qcwb = (unsigned short*)(ws + 8192 + 165888); // 110592 B

    hipMemsetAsync(stats, 0, (size_t)NB * 384 * sizeof(float), stream);

    prep_qcw_kernel<<<216, 256, 0, stream>>>(qk_w, qk_dw, qcwb);
    fused_qk_stats_kernel<<<dim3(256, NB), 256, 0, stream>>>(fea0, qcwb, stats);
    softmax_w2_cw_kernel<<<NB, 256, 0, stream>>>(stats, proj_w, temperature, v_w, v_dw, cwb);
    conv3x3_out_kernel<<<dim3(256, NB), 256, 0, stream>>>(fea1, cwb, out);
}